// Round 13
// baseline (511.313 us; speedup 1.0000x reference)
//
#include <hip/hip_runtime.h>

#define NPIX (512*512)   // 262144
#define NROWS 32         // 8 images x 4 channels
#define NBH 16384        // reachable code space: pre_loss<1 => code <= 0x3F80

__device__ inline float wredf_(float v){
  #pragma unroll
  for (int o=32;o>0;o>>=1) v += __shfl_down(v, o);
  return v;
}

// RTNE round of f32 to its top-16 bits. Monotone in v for v>=0.
__device__ inline unsigned rtne16_(float v){
  unsigned u = __float_as_uint(v);
  return (u + 0x7FFFu + ((u>>16)&1u)) >> 16;
}

// ---------------------------------------------------------------------------
// MEGA PASS v2 — histogram folded in via GLOBAL atomics; negc intermediate
// ELIMINATED (R12 post-mortem: k_hist's 16.8MB round-trip + 3.8M LDS atomics
// + ~4M flush atomics cost ~36us; the fine histogram can be built directly
// here with fire-and-forget global atomics hidden under the pass's ~85% idle
// latency). Zeros are skipped entirely: they add 0 to the top-k sum, and the
// cut-in-zeros case is k_items' total<k path.
// grid: 8 img x 256 chunks = 2048 blocks; 4 consecutive positions/thread.
// segacc[q*8+img], q: 0=bce1 1=i1 2=x1 3=t1 4=bce2 5=i2 6=x2 7=t2
// ---------------------------------------------------------------------------
__global__ __launch_bounds__(256, 4) void k_mega(
  const float* __restrict__ us, const float* __restrict__ inputs,
  const float* __restrict__ train_mask, const float* __restrict__ tr_mask,
  const float* __restrict__ label,
  unsigned* __restrict__ hc,
  float* __restrict__ pos_cf, float* __restrict__ pos_s,
  float* __restrict__ segacc)
{
  int tid = threadIdx.x;
  int img = blockIdx.x>>8, chunk = blockIdx.x&255;
  int p0 = chunk*1024 + tid*4;
  size_t gp = (size_t)img*NPIX + p0;

  // ---- issue ALL loads first: 12 independent dwordx4 in flight ----
  float4 tm4 = *(const float4*)(train_mask + gp);
  float4 lb4 = *(const float4*)(label + gp);
  const float4* t16 = (const float4*)(tr_mask + gp*4);
  float4 tv0 = t16[0], tv1 = t16[1], tv2 = t16[2], tv3 = t16[3];
  float4 xc0 = *(const float4*)(inputs + ((size_t)(img*4+0))*NPIX + p0);
  float4 xc1 = *(const float4*)(inputs + ((size_t)(img*4+1))*NPIX + p0);
  float4 xc2 = *(const float4*)(inputs + ((size_t)(img*4+2))*NPIX + p0);
  float4 xc3 = *(const float4*)(inputs + ((size_t)(img*4+3))*NPIX + p0);
  float4 ua4 = *(const float4*)(us + ((size_t)img*2  )*NPIX + p0);
  float4 ub4 = *(const float4*)(us + ((size_t)img*2+1)*NPIX + p0);

  float tm[4] = {tm4.x,tm4.y,tm4.z,tm4.w};
  float lb[4] = {lb4.x,lb4.y,lb4.z,lb4.w};
  float ta_[16] = {tv0.x,tv0.y,tv0.z,tv0.w, tv1.x,tv1.y,tv1.z,tv1.w,
                   tv2.x,tv2.y,tv2.z,tv2.w, tv3.x,tv3.y,tv3.z,tv3.w};
  float xs_[16] = {xc0.x,xc0.y,xc0.z,xc0.w, xc1.x,xc1.y,xc1.z,xc1.w,
                   xc2.x,xc2.y,xc2.z,xc2.w, xc3.x,xc3.y,xc3.z,xc3.w};

  float pcf[4]={0,0,0,0}, ps[4]={0,0,0,0};
  float bce1=0.f, i1=0.f, x1s=0.f, t1s=0.f;
  float bce2=0.f, i2=0.f, x2s=0.f, t2s=0.f;

  #pragma unroll
  for (int ch=0; ch<4; ++ch){
    unsigned* hrow = hc + (size_t)(img*4+ch)*NBH;
    #pragma unroll
    for (int j=0;j<4;++j){
      float t = ta_[j*4+ch];
      float x = xs_[ch*4+j];
      float E = __expf(-fabsf(x));               // native v_exp
      float r = __builtin_amdgcn_rcpf(1.f+E);    // sigmoid(|x|)
      float s = (x>=0.f)? r : 1.f-r;             // sigmoid(x)
      float d = s - t;
      float v = d*d*tm[j];                       // pre_loss in [0,1)
      if (t >= 0.001f){ pcf[ch]+=1.f; ps[ch]+=v; }
      else {
        unsigned code = rtne16_(v);              // < 0x4000 (v<1)
        if (code) atomicAdd(&hrow[code], 1u);    // zeros skipped (add 0 to sum)
      }
      if (ch==3){                                // seg2: last channel vs label
        float tt = lb[j];
        bce2 += fmaxf(x,0.f) - x*tt + __logf(1.f+E);
        i2 += s*tt; x2s += s; t2s += tt;
      }
    }
  }

  { // seg1: us channels vs one-hot(label)
    float aa[4]={ua4.x,ua4.y,ua4.z,ua4.w};
    float bb[4]={ub4.x,ub4.y,ub4.z,ub4.w};
    #pragma unroll
    for (int j=0;j<4;++j){
      float t1 = lb[j], t0 = 1.f - t1;
      float x0=aa[j], x1=bb[j];
      float E0 = __expf(-fabsf(x0)), E1 = __expf(-fabsf(x1));
      float r0 = __builtin_amdgcn_rcpf(1.f+E0);
      float r1 = __builtin_amdgcn_rcpf(1.f+E1);
      float s0 = (x0>=0.f)? r0 : 1.f-r0;
      float s1 = (x1>=0.f)? r1 : 1.f-r1;
      bce1 += fmaxf(x0,0.f) - x0*t0 + __logf(1.f+E0);
      bce1 += fmaxf(x1,0.f) - x1*t1 + __logf(1.f+E1);
      i1 += s0*t0 + s1*t1; x1s += s0+s1; t1s += t0+t1;
    }
  }

  __shared__ float s_red[4][16];
  float red[16] = {pcf[0],pcf[1],pcf[2],pcf[3], ps[0],ps[1],ps[2],ps[3],
                   bce1, i1, x1s, t1s, bce2, i2, x2s, t2s};
  int wid = tid>>6, lane = tid&63;
  #pragma unroll
  for (int q=0;q<16;++q){
    float r = wredf_(red[q]);
    if (lane==0) s_red[wid][q] = r;
  }
  __syncthreads();
  if (tid < 16){
    float tot = s_red[0][tid]+s_red[1][tid]+s_red[2][tid]+s_red[3][tid];
    int q = tid;
    if      (q<4)  atomicAdd(&pos_cf[img*4+q], tot);
    else if (q<8)  atomicAdd(&pos_s[img*4+q-4], tot);
    else           atomicAdd(&segacc[(q-8)*8+img], tot);
  }
}

// ---------------------------------------------------------------------------
// Per-row cut + exact code-space top-k sum — fully parallel.
// 32 blocks x 256 thr. Thread t sums its 64-bin segment; Hillis-Steele
// SUFFIX scan over 256 partials; the unique owner thread re-walks its bins.
// NEW: explicit total<k guard (cut in zeros -> ssel = sum of all nonzeros),
// since zeros are no longer counted anywhere.
// ---------------------------------------------------------------------------
__global__ __launch_bounds__(256) void k_items(
  const unsigned* __restrict__ hc,
  const float* __restrict__ pos_cf, const float* __restrict__ pos_s,
  float* __restrict__ per_item)
{
  int row = blockIdx.x, tid = threadIdx.x;
  __shared__ unsigned stc[256];
  __shared__ float    sts[256];
  const unsigned* hrow = hc + (size_t)row*NBH;
  const uint4* h4 = (const uint4*)hrow;

  unsigned pc = (unsigned)pos_cf[row];
  float psv = pos_s[row];
  unsigned neg = (unsigned)NPIX - pc, k3 = 3u*pc;
  unsigned k = pc ? (neg<k3?neg:k3) : 100u;     // pos==0 -> top-100 fallback

  if (k == 0u){
    if (tid==0) per_item[row] = psv/(float)(pc?pc:1u);
    return;
  }

  unsigned tc=0u; float ts=0.f;
  #pragma unroll
  for (int j=0;j<16;++j){
    uint4 q = h4[tid*16 + j];
    unsigned ca[4]={q.x,q.y,q.z,q.w};
    int b0 = (tid*16 + j)*4;
    #pragma unroll
    for (int m=0;m<4;++m){
      if (ca[m]){
        tc += ca[m];
        ts += (float)ca[m] * __uint_as_float((unsigned)(b0+m)<<16);
      }
    }
  }
  stc[tid]=tc; sts[tid]=ts;
  __syncthreads();

  // parallel inclusive SUFFIX scan: stc[t] = sum_{t'>=t} tc[t']
  #pragma unroll
  for (int off=1; off<256; off<<=1){
    unsigned c=0u; float s=0.f;
    if (tid+off < 256){ c=stc[tid+off]; s=sts[tid+off]; }
    __syncthreads();
    stc[tid]+=c; sts[tid]+=s;
    __syncthreads();
  }

  // cut in zeros: fewer than k nonzero negs -> top-k sum = all nonzeros
  if (tid==0 && stc[0] < k){
    float ssel = sts[0];
    per_item[row] = pc ? (psv/(float)pc + ssel/(float)k) : (ssel/100.f);
    return;
  }

  unsigned above_c = (tid<255)? stc[tid+1] : 0u;
  float    above_s = (tid<255)? sts[tid+1] : 0.f;
  if (above_c < k && stc[tid] >= k){            // owner: cut in my segment
    unsigned cnt = above_c; float sum = above_s;
    int bin = -1;
    for (int b=tid*64+63; b>=tid*64; --b){
      unsigned c = hrow[b];
      if (!c) continue;
      if (cnt + c >= k){ bin=b; break; }
      cnt += c; sum += (float)c * __uint_as_float((unsigned)b<<16);
    }
    unsigned rem = k - cnt;                     // 1 <= rem <= count(bin)
    float vcut = (bin>=0)? __uint_as_float((unsigned)bin<<16) : 0.f;
    float ssel = sum + (float)rem * vcut;
    per_item[row] = pc ? (psv/(float)pc + ssel/(float)k) : (ssel/100.f);
  }
}

// ---------------------------------------------------------------------------
// Scalar assembly. segacc[q*8+img]. Output: (h<<16)|h dual f32/bf16 encoding.
// ---------------------------------------------------------------------------
__global__ __launch_bounds__(64) void k_scalar(
  const float* __restrict__ per_item, const float* __restrict__ segacc,
  const float* __restrict__ swp, unsigned* __restrict__ out)
{
  int tid = threadIdx.x;
  float v = (tid<NROWS)? per_item[tid] : 0.f;
  v = wredf_(v);
  __shared__ float s_l;
  if (tid==0) s_l = v;
  __syncthreads();
  if (tid != 0) return;

  double lsum = (double)s_l;
  double sw = (double)swp[0];
  double loss = (lsum/8.0)/(2.0*sw*sw + 1e-6) - log(sw);
  double bce1=0.0, bce2=0.0, d1=0.0, d2=0.0;
  for (int i=0;i<8;++i){
    bce1 += (double)segacc[i];
    bce2 += (double)segacc[32+i];
    d1 += (2.0*(double)segacc[8+i]  + 1e-5)/((double)segacc[16+i] + (double)segacc[24+i] + 1e-5);
    d2 += (2.0*(double)segacc[40+i] + 1e-5)/((double)segacc[48+i] + (double)segacc[56+i] + 1e-5);
  }
  double seg1 = 0.5*(bce1/(2.0*8.0*(double)NPIX)) + (1.0 - d1/8.0);
  double seg2 = 0.5*(bce2/(8.0*(double)NPIX))     + (1.0 - d2/8.0);
  float tot = (float)(seg1 + seg2 + loss);
  unsigned u = __float_as_uint(tot);
  unsigned h = (u + 0x7FFFu + ((u>>16)&1u)) >> 16;   // RTNE bf16 bits
  out[0] = (h<<16) | h;
}

// ---------------------------------------------------------------------------
extern "C" void kernel_launch(void* const* d_in, const int* in_sizes, int n_in,
                              void* d_out, int out_size, void* d_ws, size_t ws_size,
                              hipStream_t stream)
{
  const float* us         = (const float*)d_in[0];  // (8,2,512,512)
  const float* inputs     = (const float*)d_in[1];  // (8,4,512,512)
  const float* train_mask = (const float*)d_in[2];  // (8,1,512,512)
  const float* tr_mask    = (const float*)d_in[3];  // (8,512,512,4)
  const float* label      = (const float*)d_in[4];  // (8,1,512,512)
  const float* sw         = (const float*)d_in[5];  // (1,)

  char* w = (char*)d_ws;
  size_t off = 0;
  unsigned* hc    = (unsigned*)(w+off); off += (size_t)NROWS*NBH*4;  // 2MB
  float*    pos_cf= (float*)(w+off);    off += NROWS*4;
  float*    pos_s = (float*)(w+off);    off += NROWS*4;
  float*    segacc= (float*)(w+off);    off += 64*4;
  size_t zbytes = off;                               // ~2MB zeroed each call
  float*    perit = (float*)(w+off);    off += NROWS*4;  // always written

  hipMemsetAsync(w, 0, zbytes, stream);

  k_mega  <<<dim3(2048), dim3(256), 0, stream>>>(us, inputs, train_mask, tr_mask,
                                                 label, hc, pos_cf, pos_s, segacc);
  k_items <<<dim3(NROWS),dim3(256), 0, stream>>>(hc, pos_cf, pos_s, perit);
  k_scalar<<<dim3(1),    dim3(64),  0, stream>>>(perit, segacc, sw, (unsigned*)d_out);
}

// Round 14
// 80.752 us; speedup vs baseline: 6.3319x; 6.3319x over previous
//
#include <hip/hip_runtime.h>

#define NPIX (512*512)   // 262144
#define NROWS 32         // 8 images x 4 channels
#define NBIN 256         // half-octave bins: code>>6, code = f32bits>>16 (<1.0 => bin<=254)

__device__ inline float wredf_(float v){
  #pragma unroll
  for (int o=32;o>0;o>>=1) v += __shfl_down(v, o);
  return v;
}

// RTNE round of f32 to its top-16 bits. Monotone in v for v>=0.
__device__ inline unsigned rtne16_(float v){
  unsigned u = __float_as_uint(v);
  return (u + 0x7FFFu + ((u>>16)&1u)) >> 16;
}

// ---------------------------------------------------------------------------
// MEGA PASS v3 — R10 base (best measured, 54us) + in-LDS cnt+sum histogram.
// R13 lesson: per-element GLOBAL atomics = 500us (RMW ~300GB/s). Histogram
// lives in LDS (2 copies to halve same-address chains), flushed per-block
// (<=2048 global atomics/block, <=256-deep per address -- proven fine).
// negc intermediate + k_hist kernel eliminated: -34MB traffic, -1 launch.
// grid: 8 img x 256 chunks = 2048 blocks; 4 consecutive positions/thread.
// segacc: [0]=bce1 [1]=bce2 [2..9]=i1 [10..17]=x1 [18..25]=t1
//         [26..33]=i2 [34..41]=x2 [42..49]=t2   (R10 layout)
// ---------------------------------------------------------------------------
__global__ __launch_bounds__(256, 4) void k_mega(
  const float* __restrict__ us, const float* __restrict__ inputs,
  const float* __restrict__ train_mask, const float* __restrict__ tr_mask,
  const float* __restrict__ label,
  unsigned* __restrict__ ghc, float* __restrict__ ghs,
  float* __restrict__ pos_cf, float* __restrict__ pos_s,
  float* __restrict__ segacc)
{
  __shared__ unsigned s_cnt[2*4*NBIN];   // [copy][ch][bin], 8KB
  __shared__ float    s_sum[2*4*NBIN];   // 8KB
  int tid = threadIdx.x;
  for (int j=tid;j<2*4*NBIN;j+=256){ s_cnt[j]=0u; s_sum[j]=0.f; }
  __syncthreads();

  int img = blockIdx.x>>8, chunk = blockIdx.x&255;
  int p0 = chunk*1024 + tid*4;
  size_t gp = (size_t)img*NPIX + p0;
  int cpy = (tid&1)*4*NBIN;

  // ---- issue ALL loads first: 12 independent dwordx4 in flight ----
  float4 tm4 = *(const float4*)(train_mask + gp);
  float4 lb4 = *(const float4*)(label + gp);
  const float4* t16 = (const float4*)(tr_mask + gp*4);
  float4 tv0 = t16[0], tv1 = t16[1], tv2 = t16[2], tv3 = t16[3];
  float4 xc0 = *(const float4*)(inputs + ((size_t)(img*4+0))*NPIX + p0);
  float4 xc1 = *(const float4*)(inputs + ((size_t)(img*4+1))*NPIX + p0);
  float4 xc2 = *(const float4*)(inputs + ((size_t)(img*4+2))*NPIX + p0);
  float4 xc3 = *(const float4*)(inputs + ((size_t)(img*4+3))*NPIX + p0);
  float4 ua4 = *(const float4*)(us + ((size_t)img*2  )*NPIX + p0);
  float4 ub4 = *(const float4*)(us + ((size_t)img*2+1)*NPIX + p0);

  float tm[4] = {tm4.x,tm4.y,tm4.z,tm4.w};
  float lb[4] = {lb4.x,lb4.y,lb4.z,lb4.w};
  float ta_[16] = {tv0.x,tv0.y,tv0.z,tv0.w, tv1.x,tv1.y,tv1.z,tv1.w,
                   tv2.x,tv2.y,tv2.z,tv2.w, tv3.x,tv3.y,tv3.z,tv3.w};
  float xs_[16] = {xc0.x,xc0.y,xc0.z,xc0.w, xc1.x,xc1.y,xc1.z,xc1.w,
                   xc2.x,xc2.y,xc2.z,xc2.w, xc3.x,xc3.y,xc3.z,xc3.w};

  float pcf[4]={0,0,0,0}, ps[4]={0,0,0,0};
  unsigned zc[4]={0,0,0,0};
  float bce1=0.f, i1=0.f, x1s=0.f, t1s=0.f;
  float bce2=0.f, i2=0.f, x2s=0.f, t2s=0.f;

  #pragma unroll
  for (int ch=0; ch<4; ++ch){
    #pragma unroll
    for (int j=0;j<4;++j){
      float t = ta_[j*4+ch];
      float x = xs_[ch*4+j];
      float E = __expf(-fabsf(x));               // native v_exp
      float r = __builtin_amdgcn_rcpf(1.f+E);    // sigmoid(|x|)
      float s = (x>=0.f)? r : 1.f-r;             // sigmoid(x)
      float d = s - t;
      float v = d*d*tm[j];                       // pre_loss in [0,1)
      if (t >= 0.001f){ pcf[ch]+=1.f; ps[ch]+=v; }
      else {
        unsigned code = rtne16_(v);              // <= 0x3F80
        if (code == 0u) zc[ch]++;                // zero-class: registers
        else {
          int b = cpy + ch*NBIN + (int)(code>>6);
          atomicAdd(&s_cnt[b], 1u);
          atomicAdd(&s_sum[b], v);
        }
      }
      if (ch==3){                                // seg2: last channel vs label
        float tt = lb[j];
        bce2 += fmaxf(x,0.f) - x*tt + __logf(1.f+E);
        i2 += s*tt; x2s += s; t2s += tt;
      }
    }
  }

  { // seg1: us channels vs one-hot(label)
    float aa[4]={ua4.x,ua4.y,ua4.z,ua4.w};
    float bb[4]={ub4.x,ub4.y,ub4.z,ub4.w};
    #pragma unroll
    for (int j=0;j<4;++j){
      float t1 = lb[j], t0 = 1.f - t1;
      float x0=aa[j], x1=bb[j];
      float E0 = __expf(-fabsf(x0)), E1 = __expf(-fabsf(x1));
      float r0 = __builtin_amdgcn_rcpf(1.f+E0);
      float r1 = __builtin_amdgcn_rcpf(1.f+E1);
      float s0 = (x0>=0.f)? r0 : 1.f-r0;
      float s1 = (x1>=0.f)? r1 : 1.f-r1;
      bce1 += fmaxf(x0,0.f) - x0*t0 + __logf(1.f+E0);
      bce1 += fmaxf(x1,0.f) - x1*t1 + __logf(1.f+E1);
      i1 += s0*t0 + s1*t1; x1s += s0+s1; t1s += t0+t1;
    }
  }

  #pragma unroll
  for (int ch=0;ch<4;++ch)
    if (zc[ch]) atomicAdd(&s_cnt[cpy + ch*NBIN], zc[ch]);  // bin 0, cnt only

  __shared__ float s_red[4][16];
  float red[16] = {pcf[0],pcf[1],pcf[2],pcf[3], ps[0],ps[1],ps[2],ps[3],
                   bce1, i1, x1s, t1s, bce2, i2, x2s, t2s};
  int wid = tid>>6, lane = tid&63;
  #pragma unroll
  for (int q=0;q<16;++q){
    float r = wredf_(red[q]);
    if (lane==0) s_red[wid][q] = r;
  }
  __syncthreads();
  if (tid < 16){
    float tot = s_red[0][tid]+s_red[1][tid]+s_red[2][tid]+s_red[3][tid];
    int q = tid;
    if      (q<4)   atomicAdd(&pos_cf[img*4+q], tot);
    else if (q<8)   atomicAdd(&pos_s[img*4+q-4], tot);
    else if (q==8)  atomicAdd(&segacc[0], tot);
    else if (q==9)  atomicAdd(&segacc[2+img], tot);
    else if (q==10) atomicAdd(&segacc[10+img], tot);
    else if (q==11) atomicAdd(&segacc[18+img], tot);
    else if (q==12) atomicAdd(&segacc[1], tot);
    else if (q==13) atomicAdd(&segacc[26+img], tot);
    else if (q==14) atomicAdd(&segacc[34+img], tot);
    else            atomicAdd(&segacc[42+img], tot);
  }

  // flush merged histogram partials (<=2048 atomics/block, 256-deep chains)
  for (int j=tid;j<4*NBIN;j+=256){
    unsigned c = s_cnt[j] + s_cnt[4*NBIN+j];
    float    s = s_sum[j] + s_sum[4*NBIN+j];
    int ch = j>>8, bin = j&255;
    if (c)      atomicAdd(&ghc[(img*4+ch)*NBIN + bin], c);
    if (s!=0.f) atomicAdd(&ghs[(img*4+ch)*NBIN + bin], s);
  }
}

// ---------------------------------------------------------------------------
// Per-row cut + top-k sum from the 256-bin cnt+sum histogram.
// 32 blocks x 256 thr; thread t owns bin t; parallel SUFFIX scan; the owner
// bin applies R6's proven order-statistics boundary correction:
// mtop = mean + 0.5*wdt*(1 - rem/cnt)  (uniform-within-bin model).
// ---------------------------------------------------------------------------
__global__ __launch_bounds__(256) void k_items(
  const unsigned* __restrict__ ghc, const float* __restrict__ ghs,
  const float* __restrict__ pos_cf, const float* __restrict__ pos_s,
  float* __restrict__ per_item)
{
  int row = blockIdx.x, tid = threadIdx.x;
  __shared__ unsigned stc[256];
  __shared__ float    sts[256];

  unsigned pc = (unsigned)pos_cf[row];
  float psv = pos_s[row];
  unsigned neg = (unsigned)NPIX - pc, k3 = 3u*pc;
  unsigned k = pc ? (neg<k3?neg:k3) : 100u;     // pos==0 -> top-100 fallback

  if (k == 0u){
    if (tid==0) per_item[row] = psv/(float)(pc?pc:1u);
    return;
  }

  unsigned c0 = ghc[row*NBIN + tid];
  float    s0 = ghs[row*NBIN + tid];
  stc[tid]=c0; sts[tid]=s0;
  __syncthreads();

  // parallel inclusive SUFFIX scan: stc[t] = sum_{t'>=t} cnt[t']
  #pragma unroll
  for (int off=1; off<256; off<<=1){
    unsigned c=0u; float s=0.f;
    if (tid+off < 256){ c=stc[tid+off]; s=sts[tid+off]; }
    __syncthreads();
    stc[tid]+=c; sts[tid]+=s;
    __syncthreads();
  }

  // cut below all counted bins (inside zero-class tail): sum = all nonzeros
  if (tid==0 && stc[0] < k){
    float ssel = sts[0];
    per_item[row] = pc ? (psv/(float)pc + ssel/(float)k) : (ssel/100.f);
    return;
  }

  unsigned above_c = (tid<255)? stc[tid+1] : 0u;
  float    above_s = (tid<255)? sts[tid+1] : 0.f;
  if (above_c < k && stc[tid] >= k){            // owner bin
    unsigned rem = k - above_c;                 // 1 <= rem <= c0
    float mean = s0 / (float)c0;
    float lo = __uint_as_float(((unsigned)tid<<6)<<16);
    float hi = __uint_as_float((((unsigned)tid+1u)<<6)<<16);
    float wdt = hi - lo;
    float mtop = mean + 0.5f*wdt*(1.f - (float)rem/(float)c0);
    mtop = fminf(fmaxf(mtop, lo), hi);          // safety clamp
    float ssel = above_s + (float)rem * mtop;
    per_item[row] = pc ? (psv/(float)pc + ssel/(float)k) : (ssel/100.f);
  }
}

// ---------------------------------------------------------------------------
// Scalar assembly (R10 segacc layout). Output: (h<<16)|h dual f32/bf16.
// ---------------------------------------------------------------------------
__global__ __launch_bounds__(64) void k_scalar(
  const float* __restrict__ per_item, const float* __restrict__ segacc,
  const float* __restrict__ swp, unsigned* __restrict__ out)
{
  int tid = threadIdx.x;
  float v = (tid<NROWS)? per_item[tid] : 0.f;
  v = wredf_(v);
  __shared__ float s_l;
  if (tid==0) s_l = v;
  __syncthreads();
  if (tid != 0) return;

  double lsum = (double)s_l;
  double sw = (double)swp[0];
  double loss = (lsum/8.0)/(2.0*sw*sw + 1e-6) - log(sw);
  double d1=0.0, d2=0.0;
  for (int i=0;i<8;++i){
    d1 += (2.0*(double)segacc[2+i]  + 1e-5)/((double)segacc[10+i] + (double)segacc[18+i] + 1e-5);
    d2 += (2.0*(double)segacc[26+i] + 1e-5)/((double)segacc[34+i] + (double)segacc[42+i] + 1e-5);
  }
  double seg1 = 0.5*((double)segacc[0]/(2.0*8.0*(double)NPIX)) + (1.0 - d1/8.0);
  double seg2 = 0.5*((double)segacc[1]/(8.0*(double)NPIX))     + (1.0 - d2/8.0);
  float tot = (float)(seg1 + seg2 + loss);
  unsigned u = __float_as_uint(tot);
  unsigned h = (u + 0x7FFFu + ((u>>16)&1u)) >> 16;   // RTNE bf16 bits
  out[0] = (h<<16) | h;
}

// ---------------------------------------------------------------------------
extern "C" void kernel_launch(void* const* d_in, const int* in_sizes, int n_in,
                              void* d_out, int out_size, void* d_ws, size_t ws_size,
                              hipStream_t stream)
{
  const float* us         = (const float*)d_in[0];  // (8,2,512,512)
  const float* inputs     = (const float*)d_in[1];  // (8,4,512,512)
  const float* train_mask = (const float*)d_in[2];  // (8,1,512,512)
  const float* tr_mask    = (const float*)d_in[3];  // (8,512,512,4)
  const float* label      = (const float*)d_in[4];  // (8,1,512,512)
  const float* sw         = (const float*)d_in[5];  // (1,)

  char* w = (char*)d_ws;
  size_t off = 0;
  unsigned* ghc   = (unsigned*)(w+off); off += (size_t)NROWS*NBIN*4;  // 32KB
  float*    ghs   = (float*)(w+off);    off += (size_t)NROWS*NBIN*4;  // 32KB
  float*    pos_cf= (float*)(w+off);    off += NROWS*4;
  float*    pos_s = (float*)(w+off);    off += NROWS*4;
  float*    segacc= (float*)(w+off);    off += 64*4;
  size_t zbytes = off;                               // ~66KB zeroed each call
  float*    perit = (float*)(w+off);    off += NROWS*4;  // always written

  hipMemsetAsync(w, 0, zbytes, stream);

  k_mega  <<<dim3(2048), dim3(256), 0, stream>>>(us, inputs, train_mask, tr_mask,
                                                 label, ghc, ghs,
                                                 pos_cf, pos_s, segacc);
  k_items <<<dim3(NROWS),dim3(256), 0, stream>>>(ghc, ghs, pos_cf, pos_s, perit);
  k_scalar<<<dim3(1),    dim3(64),  0, stream>>>(perit, segacc, sw, (unsigned*)d_out);
}